// Round 1
// baseline (872.699 us; speedup 1.0000x reference)
//
#include <hip/hip_runtime.h>

#define LN_EPS 1e-5f
#define AVG_K 151
#define AVG_HALF 75

// ---------------- block reduce ----------------
__device__ inline float blockReduceSum(float val, float* tmp) {
  #pragma unroll
  for (int off = 32; off > 0; off >>= 1) val += __shfl_down(val, off, 64);
  int lane = threadIdx.x & 63;
  int wid  = threadIdx.x >> 6;
  __syncthreads();
  if (lane == 0) tmp[wid] = val;
  __syncthreads();
  int nw = blockDim.x >> 6;
  val = (threadIdx.x < nw) ? tmp[threadIdx.x] : 0.f;
  if (wid == 0) {
    #pragma unroll
    for (int off = 32; off > 0; off >>= 1) val += __shfl_down(val, off, 64);
  }
  return val;  // valid on thread 0
}

// ---------------- 1: sum / sumsq of x ----------------
__global__ void k_reduce_x(const float* __restrict__ x, int L, float* __restrict__ sums) {
  __shared__ float tmp[16];
  float s = 0.f, ss = 0.f;
  for (int j = blockIdx.x * blockDim.x + threadIdx.x; j < L; j += gridDim.x * blockDim.x) {
    float val = x[j];
    s += val; ss += val * val;
  }
  float bs  = blockReduceSum(s, tmp);
  float bss = blockReduceSum(ss, tmp);
  if (threadIdx.x == 0) { atomicAdd(&sums[0], bs); atomicAdd(&sums[1], bss); }
}

// ---------------- 2: collapse Wb over pred dim ----------------
__global__ void k_prep(const float* __restrict__ W1b, const float* __restrict__ b1b,
                       const float* __restrict__ W2b, const float* __restrict__ b2b,
                       float* __restrict__ wb1, float* __restrict__ wb2,
                       float* __restrict__ bbs) {
  int tid = threadIdx.x;
  for (int o = tid; o < 260; o += blockDim.x) {
    float s = 0.f;
    #pragma unroll
    for (int p = 0; p < 3; ++p) s += W1b[p * 260 + o];
    wb1[o] = s * (1.f / 3.f);
  }
  for (int o = tid; o < 516; o += blockDim.x) {
    float s = 0.f;
    for (int p = 0; p < 21; ++p) s += W2b[p * 516 + o];
    wb2[o] = s * (1.f / 21.f);
  }
  if (tid == 0) {
    float s = 0.f;
    for (int p = 0; p < 3; ++p) s += b1b[p];
    bbs[0] = s * (1.f / 3.f);
    s = 0.f;
    for (int p = 0; p < 21; ++p) s += b2b[p];
    bbs[1] = s * (1.f / 21.f);
  }
}

// ---------------- 3: v = layernorm(x) ----------------
__global__ void k_normalize(const float* __restrict__ x, const float* __restrict__ sums,
                            float* __restrict__ v, int L) {
  float mean = sums[0] / (float)L;
  float var  = sums[1] / (float)L - mean * mean;
  float rstd = rsqrtf(var + LN_EPS);
  for (int j = blockIdx.x * blockDim.x + threadIdx.x; j < L; j += gridDim.x * blockDim.x) {
    v[j] = (x[j] - mean) * rstd;
  }
}

// ---------------- 4: avgpool151 of v and v*v (zero pad) ----------------
__global__ void k_avgpool(const float* __restrict__ v, float* __restrict__ avg,
                          float* __restrict__ energy, int L) {
  __shared__ float sv[256 + 2 * AVG_HALF];
  const int tid = threadIdx.x;
  const int j0 = blockIdx.x * 256;
  for (int m = tid; m < 256 + 2 * AVG_HALF; m += 256) {
    int idx = j0 - AVG_HALF + m;
    sv[m] = (idx >= 0 && idx < L) ? v[idx] : 0.f;
  }
  __syncthreads();
  float s = 0.f, e = 0.f;
  #pragma unroll 1
  for (int t = 0; t < AVG_K; ++t) {
    float val = sv[tid + t];
    s += val;
    e += val * val;
  }
  avg[j0 + tid]    = s * (1.f / AVG_K);
  energy[j0 + tid] = e * (1.f / AVG_K);
}

// ---------------- 5/6: band GEMM branch ----------------
// A[j,i] = v[(j-i) mod L] for i<D-1, A[j,D-1] = avg[j]
// t[j] += sum_{o in [obase,obase+ocount)} relu(dot(A[j],Wa[o]) + ba[o]) * wbe[o]  (+ bb once)
template <int D, int OC>
__global__ __launch_bounds__(128) void k_branch(
    const float* __restrict__ v, const float* __restrict__ avgv,
    const float* __restrict__ Wa, const float* __restrict__ ba,
    const float* __restrict__ wbe, const float* __restrict__ bbs, int bb_idx,
    float* __restrict__ t, int L, int ocount) {
  __shared__ float sA[512 + D - 1];
  __shared__ float sAvg[512];
  const int tid = threadIdx.x;
  const int j0 = blockIdx.x * 512;
  const int mask = L - 1;  // L is a power of two (262144)

  for (int m = tid; m < 512 + D - 1; m += 128) {
    sA[m] = v[(j0 - (D - 1) + m + L) & mask];
  }
  for (int m = tid; m < 512; m += 128) sAvg[m] = avgv[j0 + m];
  __syncthreads();

  const int obase = blockIdx.y * ocount;
  float acc0 = 0.f, acc1 = 0.f, acc2s = 0.f, acc3 = 0.f;

  const float av0 = sAvg[4 * tid + 0];
  const float av1 = sAvg[4 * tid + 1];
  const float av2 = sAvg[4 * tid + 2];
  const float av3 = sAvg[4 * tid + 3];

  for (int oc0 = obase; oc0 < obase + ocount; oc0 += OC) {
    float acc[4][OC];
    #pragma unroll
    for (int q = 0; q < 4; ++q)
      #pragma unroll
      for (int oc = 0; oc < OC; ++oc) acc[q][oc] = 0.f;

    // sliding window registers: w_q = sA[4*tid + q + (D-1) - i]
    float w0 = sA[4 * tid + (D - 1) + 0];
    float w1 = sA[4 * tid + (D - 1) + 1];
    float w2 = sA[4 * tid + (D - 1) + 2];
    float w3 = sA[4 * tid + (D - 1) + 3];

    #pragma unroll 4
    for (int i = 0; i < D - 1; ++i) {
      float wa[OC];
      #pragma unroll
      for (int oc = 0; oc < OC; ++oc) wa[oc] = Wa[(oc0 + oc) * D + i];  // uniform -> s_load
      #pragma unroll
      for (int oc = 0; oc < OC; ++oc) {
        acc[0][oc] += w0 * wa[oc];
        acc[1][oc] += w1 * wa[oc];
        acc[2][oc] += w2 * wa[oc];
        acc[3][oc] += w3 * wa[oc];
      }
      w3 = w2; w2 = w1; w1 = w0;
      w0 = sA[4 * tid + (D - 2) - i];
    }

    // avg row (i = D-1)
    #pragma unroll
    for (int oc = 0; oc < OC; ++oc) {
      float wl = Wa[(oc0 + oc) * D + (D - 1)];
      acc[0][oc] += av0 * wl;
      acc[1][oc] += av1 * wl;
      acc[2][oc] += av2 * wl;
      acc[3][oc] += av3 * wl;
    }

    // relu + wb_eff contraction
    #pragma unroll
    for (int oc = 0; oc < OC; ++oc) {
      float b = ba[oc0 + oc];
      float we = wbe[oc0 + oc];
      float h0 = fmaxf(acc[0][oc] + b, 0.f);
      float h1 = fmaxf(acc[1][oc] + b, 0.f);
      float h2 = fmaxf(acc[2][oc] + b, 0.f);
      float h3 = fmaxf(acc[3][oc] + b, 0.f);
      acc0 += h0 * we; acc1 += h1 * we; acc2s += h2 * we; acc3 += h3 * we;
    }
  }

  float bb = (blockIdx.y == 0) ? bbs[bb_idx] : 0.f;
  atomicAdd(&t[j0 + 4 * tid + 0], acc0 + bb);
  atomicAdd(&t[j0 + 4 * tid + 1], acc1 + bb);
  atomicAdd(&t[j0 + 4 * tid + 2], acc2s + bb);
  atomicAdd(&t[j0 + 4 * tid + 3], acc3 + bb);
}

// ---------------- 7: u1 = t1/energy (in place), sums of u1 and t2 ----------------
__global__ void k_reduce_t(float* __restrict__ t1, const float* __restrict__ t2,
                           const float* __restrict__ energy, float* __restrict__ sums, int L) {
  __shared__ float tmp[16];
  float s1 = 0.f, s11 = 0.f, s2 = 0.f, s22 = 0.f;
  for (int j = blockIdx.x * blockDim.x + threadIdx.x; j < L; j += gridDim.x * blockDim.x) {
    float u = t1[j] / energy[j];
    t1[j] = u;
    s1 += u; s11 += u * u;
    float w = t2[j];
    s2 += w; s22 += w * w;
  }
  float r;
  r = blockReduceSum(s1, tmp);  if (threadIdx.x == 0) atomicAdd(&sums[2], r);
  r = blockReduceSum(s11, tmp); if (threadIdx.x == 0) atomicAdd(&sums[3], r);
  r = blockReduceSum(s2, tmp);  if (threadIdx.x == 0) atomicAdd(&sums[4], r);
  r = blockReduceSum(s22, tmp); if (threadIdx.x == 0) atomicAdd(&sums[5], r);
}

// ---------------- 8: final layernorms ----------------
__global__ void k_final(const float* __restrict__ t1, const float* __restrict__ t2,
                        const float* __restrict__ sums, float* __restrict__ out, int L) {
  float m1 = sums[2] / (float)L;
  float v1 = sums[3] / (float)L - m1 * m1;
  float r1 = rsqrtf(v1 + LN_EPS);
  float m2 = sums[4] / (float)L;
  float v2 = sums[5] / (float)L - m2 * m2;
  float r2 = rsqrtf(v2 + LN_EPS);
  for (int j = blockIdx.x * blockDim.x + threadIdx.x; j < L; j += gridDim.x * blockDim.x) {
    out[j]     = (t1[j] - m1) * r1;
    out[L + j] = (t2[j] - m2) * r2;
  }
}

extern "C" void kernel_launch(void* const* d_in, const int* in_sizes, int n_in,
                              void* d_out, int out_size, void* d_ws, size_t ws_size,
                              hipStream_t stream) {
  const float* x   = (const float*)d_in[0];
  const float* W1a = (const float*)d_in[1];
  const float* b1a = (const float*)d_in[2];
  const float* W1b = (const float*)d_in[3];
  const float* b1b = (const float*)d_in[4];
  const float* W2a = (const float*)d_in[5];
  const float* b2a = (const float*)d_in[6];
  const float* W2b = (const float*)d_in[7];
  const float* b2b = (const float*)d_in[8];
  float* out = (float*)d_out;

  const int L = in_sizes[0];  // 262144 (power of two)
  float* ws = (float*)d_ws;
  float* v      = ws;
  float* avg    = ws + (size_t)L;
  float* energy = ws + 2 * (size_t)L;
  float* t1     = ws + 3 * (size_t)L;
  float* t2     = ws + 4 * (size_t)L;
  float* sums   = ws + 5 * (size_t)L;        // 8 slots
  float* wb1    = sums + 8;                  // 260
  float* wb2    = wb1 + 260;                 // 516
  float* bbs    = wb2 + 516;                 // 2

  // zero t1, t2, sums (contiguous)
  hipMemsetAsync(t1, 0, (2 * (size_t)L + 8) * sizeof(float), stream);

  k_reduce_x<<<1024, 256, 0, stream>>>(x, L, sums);
  k_prep<<<1, 256, 0, stream>>>(W1b, b1b, W2b, b2b, wb1, wb2, bbs);
  k_normalize<<<1024, 256, 0, stream>>>(x, sums, v, L);
  k_avgpool<<<L / 256, 256, 0, stream>>>(v, avg, energy, L);

  dim3 gb(L / 512, 2);
  k_branch<65, 10><<<gb, 128, 0, stream>>>(v, avg, W1a, b1a, wb1, bbs, 0, t1, L, 130);
  k_branch<129, 6><<<gb, 128, 0, stream>>>(v, avg, W2a, b2a, wb2, bbs, 1, t2, L, 258);

  k_reduce_t<<<1024, 256, 0, stream>>>(t1, t2, energy, sums, L);
  k_final<<<1024, 256, 0, stream>>>(t1, t2, sums, out, L);
}

// Round 3
// 364.088 us; speedup vs baseline: 2.3969x; 2.3969x over previous
//
#include <hip/hip_runtime.h>
#include <hip/hip_bf16.h>

#define LN_EPS 1e-5f
#define AVG_K 151
#define AVG_HALF 75

typedef __attribute__((ext_vector_type(8))) short short8v;
typedef __attribute__((ext_vector_type(4))) float float4v;

static __device__ inline float bf2f(unsigned short u) {
  unsigned int x = ((unsigned int)u) << 16;
  union { unsigned int i; float f; } cv; cv.i = x; return cv.f;
}
static __device__ inline unsigned short f2bf(float f) {
  union { __hip_bfloat16 h; unsigned short u; } cv;
  cv.h = __float2bfloat16(f);
  return cv.u;
}

// ---------------- block reduce ----------------
__device__ inline float blockReduceSum(float val, float* tmp) {
  #pragma unroll
  for (int off = 32; off > 0; off >>= 1) val += __shfl_down(val, off, 64);
  int lane = threadIdx.x & 63;
  int wid  = threadIdx.x >> 6;
  __syncthreads();
  if (lane == 0) tmp[wid] = val;
  __syncthreads();
  int nw = blockDim.x >> 6;
  val = (threadIdx.x < nw) ? tmp[threadIdx.x] : 0.f;
  if (wid == 0) {
    #pragma unroll
    for (int off = 32; off > 0; off >>= 1) val += __shfl_down(val, off, 64);
  }
  return val;  // valid on thread 0
}

// ---------------- 1: sum / sumsq of x ----------------
__global__ void k_reduce_x(const float* __restrict__ x, int L, float* __restrict__ sums) {
  __shared__ float tmp[16];
  float s = 0.f, ss = 0.f;
  for (int j = blockIdx.x * blockDim.x + threadIdx.x; j < L; j += gridDim.x * blockDim.x) {
    float val = x[j];
    s += val; ss += val * val;
  }
  float bs  = blockReduceSum(s, tmp);
  float bss = blockReduceSum(ss, tmp);
  if (threadIdx.x == 0) { atomicAdd(&sums[0], bs); atomicAdd(&sums[1], bss); }
}

// ---------------- 2: prep — collapse Wb, pack epilogue params, bf16 weights ----------------
// eps1[n] = {ba1[n], W1a[n][64], mean_p(W1b[p][n]), 0}  (zeros for n >= 260), n < 272
// Wb1[n*64 + k] = bf16(W1a[n][k])  (zeros for n >= 260)
// same for branch 2 with 516/528, K=128
__global__ void k_prep(const float* __restrict__ W1a, const float* __restrict__ b1a,
                       const float* __restrict__ W1b, const float* __restrict__ b1b,
                       const float* __restrict__ W2a, const float* __restrict__ b2a,
                       const float* __restrict__ W2b, const float* __restrict__ b2b,
                       float* __restrict__ eps1, float* __restrict__ eps2,
                       unsigned short* __restrict__ Wb1, unsigned short* __restrict__ Wb2,
                       float* __restrict__ sums) {
  int tid0 = blockIdx.x * blockDim.x + threadIdx.x;
  int nth = gridDim.x * blockDim.x;
  for (int n = tid0; n < 272; n += nth) {
    float ba = 0.f, waD = 0.f, wbe = 0.f;
    if (n < 260) {
      ba = b1a[n];
      waD = W1a[n * 65 + 64];
      float s = 0.f;
      #pragma unroll
      for (int p = 0; p < 3; ++p) s += W1b[p * 260 + n];
      wbe = s * (1.f / 3.f);
    }
    eps1[4 * n + 0] = ba; eps1[4 * n + 1] = waD; eps1[4 * n + 2] = wbe; eps1[4 * n + 3] = 0.f;
  }
  for (int n = tid0; n < 528; n += nth) {
    float ba = 0.f, waD = 0.f, wbe = 0.f;
    if (n < 516) {
      ba = b2a[n];
      waD = W2a[n * 129 + 128];
      float s = 0.f;
      for (int p = 0; p < 21; ++p) s += W2b[p * 516 + n];
      wbe = s * (1.f / 21.f);
    }
    eps2[4 * n + 0] = ba; eps2[4 * n + 1] = waD; eps2[4 * n + 2] = wbe; eps2[4 * n + 3] = 0.f;
  }
  for (int idx = tid0; idx < 272 * 64; idx += nth) {
    int n = idx >> 6, k = idx & 63;
    Wb1[idx] = (n < 260) ? f2bf(W1a[n * 65 + k]) : (unsigned short)0;
  }
  for (int idx = tid0; idx < 528 * 128; idx += nth) {
    int n = idx >> 7, k = idx & 127;
    Wb2[idx] = (n < 516) ? f2bf(W2a[n * 129 + k]) : (unsigned short)0;
  }
  if (tid0 == 0) {
    float s = 0.f;
    #pragma unroll
    for (int p = 0; p < 3; ++p) s += b1b[p];
    sums[6] = s * (1.f / 3.f);
    s = 0.f;
    for (int p = 0; p < 21; ++p) s += b2b[p];
    sums[7] = s * (1.f / 21.f);
  }
}

// ---------------- 3: v = layernorm(x), stored bf16 ----------------
__global__ void k_normalize(const float* __restrict__ x, const float* __restrict__ sums,
                            unsigned short* __restrict__ vb, int L) {
  float mean = sums[0] / (float)L;
  float var  = sums[1] / (float)L - mean * mean;
  float rstd = rsqrtf(var + LN_EPS);
  for (int j = blockIdx.x * blockDim.x + threadIdx.x; j < L; j += gridDim.x * blockDim.x) {
    vb[j] = f2bf((x[j] - mean) * rstd);
  }
}

// ---------------- 4: avgpool151 of v and v*v (zero pad) ----------------
__global__ void k_avgpool(const unsigned short* __restrict__ vb, float* __restrict__ avg,
                          float* __restrict__ energy, int L) {
  __shared__ float sv[256 + 2 * AVG_HALF];
  const int tid = threadIdx.x;
  const int j0 = blockIdx.x * 256;
  for (int m = tid; m < 256 + 2 * AVG_HALF; m += 256) {
    int idx = j0 - AVG_HALF + m;
    sv[m] = (idx >= 0 && idx < L) ? bf2f(vb[idx]) : 0.f;
  }
  __syncthreads();
  float s = 0.f, e = 0.f;
  #pragma unroll 1
  for (int t = 0; t < AVG_K; ++t) {
    float val = sv[tid + t];
    s += val;
    e += val * val;
  }
  avg[j0 + tid]    = s * (1.f / AVG_K);
  energy[j0 + tid] = e * (1.f / AVG_K);
}

// ---------------- 5/6: MFMA band-GEMM branch ----------------
// C[j][n] = sum_k v[(j-k) mod L] * Wa[n][k]   (Toeplitz A, K = 64 or 128)
// epilogue: h = relu(C + ba[n] + avg[j]*Wa[n][K]); t[j] = sum_n h*wbe[n] + bb
// A-fragment trick: 8 shifted copies of reversed-v window in LDS so each lane's
// 8-element (16B) fragment is a 16B-aligned ds_read_b128.
template <int K, int NT>
__global__ __launch_bounds__(256) void k_branch_mfma(
    const unsigned short* __restrict__ vb, const float* __restrict__ avg,
    const unsigned short* __restrict__ Wb, const float* __restrict__ eps,
    const float* __restrict__ sums, int bb_slot,
    float* __restrict__ t, int L) {
  constexpr int BM  = 128;
  constexpr int KB  = K / 32;
  constexpr int RC  = BM + K;       // copy length (elements)
  constexpr int RCP = RC + 8;       // padded stride -> bank stride 4 dwords per copy
  __shared__ unsigned short rc[8 * RCP];

  const int tid  = threadIdx.x;
  const int lane = tid & 63;
  const int w    = tid >> 6;        // wave id 0..3
  const int j0   = blockIdx.x * BM;
  const int mask = L - 1;           // L = 262144 (pow2); Toeplitz is circular (torch.roll)
  const int jtop = j0 + BM - 1;

  // stage: rc[c][m] = v[jtop - m - c]  (reversed window, 8 shifted copies)
  for (int idx = tid; idx < 8 * RC; idx += 256) {
    int c = idx / RC;
    int m = idx - c * RC;
    rc[c * RCP + m] = vb[(jtop - m - c + L) & mask];
  }
  __syncthreads();

  const int ll = lane & 15;
  const int h  = lane >> 4;
  const int s  = (15 - ll) + 8 * h;  // per-lane element shift, 0..23
  const int cidx  = s & 7;
  const int sbase = s & ~7;

  // A fragments in registers: rows j0+32w+16mr+ll, k = 32kb + 8h + e
  short8v afrag[2][KB];
  #pragma unroll
  for (int mr = 0; mr < 2; ++mr) {
    #pragma unroll
    for (int kb = 0; kb < KB; ++kb) {
      const int B0 = BM - 16 - 32 * w - 16 * mr + 32 * kb;
      afrag[mr][kb] = *(const short8v*)&rc[cidx * RCP + B0 + sbase];
    }
  }

  // avg per output row this lane holds (C: col=ll, row=4h+r)
  float avgreg[2][4];
  #pragma unroll
  for (int mr = 0; mr < 2; ++mr)
    #pragma unroll
    for (int r = 0; r < 4; ++r)
      avgreg[mr][r] = avg[j0 + 32 * w + 16 * mr + 4 * h + r];

  float rowacc[2][4] = {{0.f, 0.f, 0.f, 0.f}, {0.f, 0.f, 0.f, 0.f}};
  const float4* eps4 = (const float4*)eps;

  for (int nt = 0; nt < NT; ++nt) {
    const int n = nt * 16 + ll;
    short8v bfrag[KB];
    #pragma unroll
    for (int kb = 0; kb < KB; ++kb)
      bfrag[kb] = *(const short8v*)&Wb[n * K + 32 * kb + 8 * h];
    const float4 ep = eps4[n];

    #pragma unroll
    for (int mr = 0; mr < 2; ++mr) {
      float4v acc = {0.f, 0.f, 0.f, 0.f};
      #pragma unroll
      for (int kb = 0; kb < KB; ++kb)
        acc = __builtin_amdgcn_mfma_f32_16x16x32_bf16(afrag[mr][kb], bfrag[kb], acc, 0, 0, 0);
      #pragma unroll
      for (int r = 0; r < 4; ++r) {
        float hh = acc[r] + ep.x + avgreg[mr][r] * ep.y;
        hh = fmaxf(hh, 0.f);
        rowacc[mr][r] += hh * ep.z;
      }
    }
  }

  // reduce over the 16 col-lanes (same row lives in lanes with equal h)
  #pragma unroll
  for (int mr = 0; mr < 2; ++mr)
    #pragma unroll
    for (int r = 0; r < 4; ++r) {
      float vsum = rowacc[mr][r];
      vsum += __shfl_xor(vsum, 1);
      vsum += __shfl_xor(vsum, 2);
      vsum += __shfl_xor(vsum, 4);
      vsum += __shfl_xor(vsum, 8);
      rowacc[mr][r] = vsum;
    }

  const float bb = sums[bb_slot];
  if (ll == 0) {
    #pragma unroll
    for (int mr = 0; mr < 2; ++mr)
      #pragma unroll
      for (int r = 0; r < 4; ++r)
        t[j0 + 32 * w + 16 * mr + 4 * h + r] = rowacc[mr][r] + bb;
  }
}

// ---------------- 7: u1 = t1/energy (in place), sums of u1 and t2 ----------------
__global__ void k_reduce_t(float* __restrict__ t1, const float* __restrict__ t2,
                           const float* __restrict__ energy, float* __restrict__ sums, int L) {
  __shared__ float tmp[16];
  float s1 = 0.f, s11 = 0.f, s2 = 0.f, s22 = 0.f;
  for (int j = blockIdx.x * blockDim.x + threadIdx.x; j < L; j += gridDim.x * blockDim.x) {
    float u = t1[j] / energy[j];
    t1[j] = u;
    s1 += u; s11 += u * u;
    float w = t2[j];
    s2 += w; s22 += w * w;
  }
  float r;
  r = blockReduceSum(s1, tmp);  if (threadIdx.x == 0) atomicAdd(&sums[2], r);
  r = blockReduceSum(s11, tmp); if (threadIdx.x == 0) atomicAdd(&sums[3], r);
  r = blockReduceSum(s2, tmp);  if (threadIdx.x == 0) atomicAdd(&sums[4], r);
  r = blockReduceSum(s22, tmp); if (threadIdx.x == 0) atomicAdd(&sums[5], r);
}

// ---------------- 8: final layernorms ----------------
__global__ void k_final(const float* __restrict__ t1, const float* __restrict__ t2,
                        const float* __restrict__ sums, float* __restrict__ out, int L) {
  float m1 = sums[2] / (float)L;
  float v1 = sums[3] / (float)L - m1 * m1;
  float r1 = rsqrtf(v1 + LN_EPS);
  float m2 = sums[4] / (float)L;
  float v2 = sums[5] / (float)L - m2 * m2;
  float r2 = rsqrtf(v2 + LN_EPS);
  for (int j = blockIdx.x * blockDim.x + threadIdx.x; j < L; j += gridDim.x * blockDim.x) {
    out[j]     = (t1[j] - m1) * r1;
    out[L + j] = (t2[j] - m2) * r2;
  }
}

extern "C" void kernel_launch(void* const* d_in, const int* in_sizes, int n_in,
                              void* d_out, int out_size, void* d_ws, size_t ws_size,
                              hipStream_t stream) {
  const float* x   = (const float*)d_in[0];
  const float* W1a = (const float*)d_in[1];
  const float* b1a = (const float*)d_in[2];
  const float* W1b = (const float*)d_in[3];
  const float* b1b = (const float*)d_in[4];
  const float* W2a = (const float*)d_in[5];
  const float* b2a = (const float*)d_in[6];
  const float* W2b = (const float*)d_in[7];
  const float* b2b = (const float*)d_in[8];
  float* out = (float*)d_out;

  const int L = in_sizes[0];  // 262144

  // workspace layout (16B-aligned sections)
  char* base = (char*)d_ws;
  float* t1     = (float*)base;                      // L
  float* t2     = t1 + L;                            // L
  float* avg    = t2 + L;                            // L
  float* energy = avg + L;                           // L
  float* sums   = energy + L;                        // 8
  float* eps1   = sums + 8;                          // 272*4
  float* eps2   = eps1 + 272 * 4;                    // 528*4
  unsigned short* vb  = (unsigned short*)(eps2 + 528 * 4);  // L
  unsigned short* Wb1 = vb + L;                      // 272*64
  unsigned short* Wb2 = Wb1 + 272 * 64;              // 528*128

  hipMemsetAsync(sums, 0, 8 * sizeof(float), stream);

  k_reduce_x<<<1024, 256, 0, stream>>>(x, L, sums);
  k_prep<<<128, 256, 0, stream>>>(W1a, b1a, W1b, b1b, W2a, b2a, W2b, b2b,
                                  eps1, eps2, Wb1, Wb2, sums);
  k_normalize<<<1024, 256, 0, stream>>>(x, sums, vb, L);
  k_avgpool<<<L / 256, 256, 0, stream>>>(vb, avg, energy, L);

  k_branch_mfma<64, 17><<<L / 128, 256, 0, stream>>>(vb, avg, Wb1, eps1, sums, 6, t1, L);
  k_branch_mfma<128, 33><<<L / 128, 256, 0, stream>>>(vb, avg, Wb2, eps2, sums, 7, t2, L);

  k_reduce_t<<<1024, 256, 0, stream>>>(t1, t2, energy, sums, L);
  k_final<<<1024, 256, 0, stream>>>(t1, t2, sums, out, L);
}